// Round 7
// baseline (352.225 us; speedup 1.0000x reference)
//
#include <hip/hip_runtime.h>
#include <hip/hip_bf16.h>

#define K_DIM 4096
#define N_DIM 4096
#define R_DIM 16
#define SCALING_F 2.0f

#define BM 256
#define BN 256
#define BK 64   // bf16 elems per K-tile; 128 bytes per LDS row

typedef __attribute__((ext_vector_type(4))) short bf16x4;
typedef __attribute__((ext_vector_type(8))) short bf16x8;
typedef __attribute__((ext_vector_type(16))) float f32x16;

__device__ __forceinline__ ushort f2bf(float f) {
  union { float f; unsigned u; } v; v.f = f;
  unsigned u = v.u;
  u += 0x7FFF + ((u >> 16) & 1);   // round-to-nearest-even
  return (ushort)(u >> 16);
}

// ---- fused pre-pass with BAKED 8B-chunk swizzle ----
// Output layout: mem[row][c8] = val[row][c8 ^ (row&15)]  (c8 = 8-byte chunk).
// GEMM stages this linearly into LDS; ds_reads apply the same XOR -> the
// 32-row fragment reads spread uniformly over all banks (b64 minimum).
__global__ __launch_bounds__(256) void prepass_kernel(
    const float* __restrict__ x, ushort* __restrict__ xb,
    const float* __restrict__ W, const float* __restrict__ A,
    const float* __restrict__ Bl, ushort* __restrict__ wb, long n4) {
  if (blockIdx.x < N_DIM) {
    int o = blockIdx.x;
    float breg[R_DIM];
#pragma unroll
    for (int r = 0; r < R_DIM; ++r) breg[r] = Bl[o * R_DIM + r] * SCALING_F;
    for (int d0 = threadIdx.x * 4; d0 < K_DIM; d0 += blockDim.x * 4) {
      float4 w = *(const float4*)(W + (size_t)o * K_DIM + d0);
      float a0 = w.x, a1 = w.y, a2 = w.z, a3 = w.w;
#pragma unroll
      for (int r = 0; r < R_DIM; ++r) {
        float4 a = *(const float4*)(A + (size_t)r * K_DIM + d0);
        a0 += breg[r] * a.x; a1 += breg[r] * a.y;
        a2 += breg[r] * a.z; a3 += breg[r] * a.w;
      }
      ushort4 ob;
      ob.x = f2bf(a0); ob.y = f2bf(a1); ob.z = f2bf(a2); ob.w = f2bf(a3);
      int cs = (d0 >> 2) ^ (o & 15);               // swizzled 8B chunk
      *(ushort4*)(wb + (size_t)o * K_DIM + (cs << 2)) = ob;
    }
  } else {
    long i = (long)(blockIdx.x - N_DIM) * blockDim.x + threadIdx.x;
    long stride = 2048L * blockDim.x;
    for (; i < n4; i += stride) {
      long idx = i * 4;
      float4 v = *(const float4*)(x + idx);
      ushort4 o;
      o.x = f2bf(v.x); o.y = f2bf(v.y); o.z = f2bf(v.z); o.w = f2bf(v.w);
      int row15 = (int)(idx >> 12) & 15;
      int cs = (((int)idx & 4095) >> 2) ^ row15;   // swizzled 8B chunk
      *(ushort4*)(xb + (idx & ~4095L) + ((long)cs << 2)) = o;
    }
  }
}

// ============================ 256x256 8-phase GEMM ============================
// r6 skeleton (stage ledger, counted vmcnt, post-MFMA same-reg prefetch)
// with 32x32x16 bf16 MFMA (2495 vs 2075 TF pipe rate) and b64 fragment reads
// under the baked 4-bit swizzle (uniform bank spread).
// 8 waves (2M x 4N); per-wave 128x64 out = 4x2 tiles of 32x32; acc[4][2] f32x16.

#define RS 8192L  // global row stride bytes (K_DIM * 2)

#define GLOAD(SRC, LOFF)                                                    \
  __builtin_amdgcn_global_load_lds(                                         \
      (const __attribute__((address_space(1))) void*)(SRC),                 \
      (__attribute__((address_space(3))) void*)(smem + (LOFF)), 16, 0, 0)

#define LDSA(BUF) ((BUF) * 32768)
#define LDSB(BUF) (65536 + (BUF) * 32768)

#define ST_A_EVEN(T, BUF) do {                                              \
    GLOAD(aS + (size_t)(T) * 128,            LDSA(BUF) + ldsDst);           \
    GLOAD(aS + (size_t)(T) * 128 + 128 * RS, LDSA(BUF) + 16384 + ldsDst); } while (0)
#define ST_A_ODD(T, BUF) do {                                               \
    GLOAD(aS + (size_t)(T) * 128 + 64 * RS,  LDSA(BUF) + 8192 + ldsDst);    \
    GLOAD(aS + (size_t)(T) * 128 + 192 * RS, LDSA(BUF) + 24576 + ldsDst); } while (0)
#define ST_B_H0(T, BUF) do {                                                \
    GLOAD(bS + (size_t)(T) * 128,            LDSB(BUF) + ldsDst);           \
    GLOAD(bS + (size_t)(T) * 128 + 64 * RS,  LDSB(BUF) + 8192 + ldsDst); } while (0)
#define ST_B_H1(T, BUF) do {                                                \
    GLOAD(bS + (size_t)(T) * 128 + 128 * RS, LDSB(BUF) + 16384 + ldsDst);   \
    GLOAD(bS + (size_t)(T) * 128 + 192 * RS, LDSB(BUF) + 24576 + ldsDst); } while (0)

// fragment = two swizzled b64 reads combined (cl/ch are literal-indexed)
#define FR(BASE, OFF, KS)                                                   \
  __builtin_shufflevector(                                                  \
      *(const bf16x4*)(smem + (BASE) + (OFF) + cl[KS]),                     \
      *(const bf16x4*)(smem + (BASE) + (OFF) + ch[KS]),                     \
      0, 1, 2, 3, 4, 5, 6, 7)

// prefetch A: m-tiles MB,MB+1, k-slices 2*KH,2*KH+1 (same-reg WAR discipline)
#define PF_A(MB, KH, BUF) do {                                              \
    afr[0][0] = FR(aRow, (MB) * 4096 + (BUF) * 32768, 2 * (KH));            \
    afr[0][1] = FR(aRow, (MB) * 4096 + (BUF) * 32768, 2 * (KH) + 1);        \
    afr[1][0] = FR(aRow, ((MB) + 1) * 4096 + (BUF) * 32768, 2 * (KH));      \
    afr[1][1] = FR(aRow, ((MB) + 1) * 4096 + (BUF) * 32768, 2 * (KH) + 1); } while (0)

#define PF_B_ALL(BUF) do {                                                  \
    _Pragma("unroll") for (int nt = 0; nt < 2; ++nt)                        \
      _Pragma("unroll") for (int ks = 0; ks < 4; ++ks)                      \
        bfr[nt][ks] = FR(bRow, nt * 4096 + (BUF) * 32768, ks); } while (0)

#define MFMA8(MB, KH) do {                                                  \
    _Pragma("unroll") for (int mm = 0; mm < 2; ++mm)                        \
      _Pragma("unroll") for (int nn = 0; nn < 2; ++nn)                      \
        _Pragma("unroll") for (int kk = 0; kk < 2; ++kk)                    \
          acc[(MB) + mm][nn] = __builtin_amdgcn_mfma_f32_32x32x16_bf16(     \
              afr[mm][kk], bfr[nn][2 * (KH) + kk], acc[(MB) + mm][nn], 0, 0, 0); } while (0)

#define PH_CORE(MB, KH) do {                                                \
    __builtin_amdgcn_s_barrier();                                           \
    asm volatile("s_waitcnt lgkmcnt(0)");                                   \
    __builtin_amdgcn_s_setprio(1);                                          \
    MFMA8(MB, KH);                                                          \
    __builtin_amdgcn_s_setprio(0); } while (0)

__global__ __launch_bounds__(512, 2) void gemm_lora_kernel(
    const ushort* __restrict__ Ab, const ushort* __restrict__ Bb,
    const float* __restrict__ bias, float* __restrict__ C) {
  __shared__ char smem[131072];

  const int tid = threadIdx.x;
  const int wave = tid >> 6, lane = tid & 63;
  const int wm = wave >> 2, wn = wave & 3;
  const int r31 = lane & 31, hi = lane >> 5;

  // XCD-aware mapping: XCD x owns bm in [4x,4x+4); bn sweeps. grid=512 (%8==0).
  const int bid = blockIdx.x;
  const int bm = ((bid & 7) << 2) + ((bid >> 3) & 3);
  const int bn = bid >> 5;

  // staging source: PLAIN linear (swizzle baked into xb/wb by prepass)
  const int trow = tid >> 3;
  const char* aS = (const char*)Ab + (size_t)(bm * BM + trow) * RS + ((tid & 7) << 4);
  const char* bS = (const char*)Bb + (size_t)(bn * BN + trow) * RS + ((tid & 7) << 4);
  const int ldsDst = tid << 4;

  // swizzled b64 read columns: chunk c8 of k-slice ks, half hi:
  //   byte = ((ks*2+hi)<<4 ^ sxh) | (j*8 ^ sxb),  s = r31&15
  const int sxh = (r31 & 14) << 3;
  const int sxb = (r31 & 1) << 3;
  const int cl[4] = {(((0 * 2 + hi) << 4) ^ sxh) | sxb,
                     (((1 * 2 + hi) << 4) ^ sxh) | sxb,
                     (((2 * 2 + hi) << 4) ^ sxh) | sxb,
                     (((3 * 2 + hi) << 4) ^ sxh) | sxb};
  const int ch[4] = {(((0 * 2 + hi) << 4) ^ sxh) | (8 ^ sxb),
                     (((1 * 2 + hi) << 4) ^ sxh) | (8 ^ sxb),
                     (((2 * 2 + hi) << 4) ^ sxh) | (8 ^ sxb),
                     (((3 * 2 + hi) << 4) ^ sxh) | (8 ^ sxb)};
  const int aRow = (wm * 128 + r31) * 128;            // + mtile*4096 + buf*32768
  const int bRow = 65536 + (wn * 64 + r31) * 128;     // + ntile*4096 + buf*32768

  f32x16 acc[4][2];
#pragma unroll
  for (int m = 0; m < 4; ++m)
#pragma unroll
    for (int n = 0; n < 2; ++n)
#pragma unroll
      for (int v = 0; v < 16; ++v) acc[m][n][v] = 0.f;
  bf16x8 afr[2][2], bfr[2][4];

  // prologue: tile0 -> buf0 (full); tile1 -> buf1 (B0,B1,Ae). 14 loads.
  ST_B_H0(0, 0); ST_B_H1(0, 0); ST_A_EVEN(0, 0); ST_A_ODD(0, 0);
  ST_B_H0(1, 1); ST_B_H1(1, 1); ST_A_EVEN(1, 1);
  asm volatile("s_waitcnt vmcnt(6)" ::: "memory");  // tile0 fully landed
  __builtin_amdgcn_s_barrier();                      // ...and visible to all
  PF_B_ALL(0);
  PF_A(0, 0, 0);

  const int NIT = K_DIM / (2 * BK);  // 32
#pragma unroll 1
  for (int i = 0; i < NIT; ++i) {
    const int t1 = 2 * i + 1, t2 = 2 * i + 2, t3 = 2 * i + 3;
    const bool last = (i == NIT - 1);

    // ---- phase 1: buf0, m-tiles 0-1, k-slices 0-1 ----
    ST_A_ODD(t1, 1);
    PH_CORE(0, 0);
    PF_A(0, 1, 0);                         // prefetch ph2 frags (ks 2-3)
    __builtin_amdgcn_s_barrier();

    // ---- phase 2: buf0, m-tiles 0-1, k-slices 2-3 ----
    if (!last) ST_B_H0(t2, 0);
    PH_CORE(0, 1);
    PF_A(2, 0, 0);                         // prefetch ph3 frags
    __builtin_amdgcn_s_barrier();

    // ---- phase 3: buf0, m-tiles 2-3, k-slices 0-1 ; t1-landing wait ----
    if (!last) ST_B_H1(t2, 0);
    PH_CORE(2, 0);
    PF_A(2, 1, 0);                         // prefetch ph4 frags
    if (last) asm volatile("s_waitcnt vmcnt(0)" ::: "memory");
    else      asm volatile("s_waitcnt vmcnt(4)" ::: "memory");
    __builtin_amdgcn_s_barrier();          // publishes buf1(t1) to all waves

    // ---- phase 4: buf0, m-tiles 2-3, k-slices 2-3 ----
    if (!last) ST_A_EVEN(t2, 0);
    PH_CORE(2, 1);
    PF_B_ALL(1);                           // prefetch ph5 frags (buf1)
    PF_A(0, 0, 1);
    __builtin_amdgcn_s_barrier();

    // ---- phase 5: buf1, m-tiles 0-1, k-slices 0-1 ----
    if (!last) ST_A_ODD(t2, 0);
    PH_CORE(0, 0);
    PF_A(0, 1, 1);                         // prefetch ph6 frags
    __builtin_amdgcn_s_barrier();

    // ---- phase 6: buf1, m-tiles 0-1, k-slices 2-3 ----
    if (!last) ST_B_H0(t3, 1);
    PH_CORE(0, 1);
    PF_A(2, 0, 1);                         // prefetch ph7 frags
    __builtin_amdgcn_s_barrier();

    // ---- phase 7: buf1, m-tiles 2-3, k-slices 0-1 ; t2-landing wait ----
    if (!last) ST_B_H1(t3, 1);
    PH_CORE(2, 0);
    PF_A(2, 1, 1);                         // prefetch ph8 frags
    if (!last) asm volatile("s_waitcnt vmcnt(4)" ::: "memory");
    __builtin_amdgcn_s_barrier();          // publishes buf0(t2) to all waves

    // ---- phase 8: buf1, m-tiles 2-3, k-slices 2-3 ----
    if (!last) ST_A_EVEN(t3, 1);
    PH_CORE(2, 1);
    if (!last) {
      PF_B_ALL(0);                         // prefetch next-iter ph1 frags
      PF_A(0, 0, 0);
      __builtin_amdgcn_s_barrier();
    }
  }

  // epilogue: 32x32 C/D layout col=lane&31, row=(reg&3)+8*(reg>>2)+4*(lane>>5)
  // [m74/m101 HW-verified; r3-passed]
  const int ccol0 = bn * BN + wn * 64 + r31;
  const float bv0 = bias[ccol0];
  const float bv1 = bias[ccol0 + 32];
  const int crow0 = bm * BM + wm * 128 + hi * 4;
#pragma unroll
  for (int mi = 0; mi < 4; ++mi)
#pragma unroll
    for (int v = 0; v < 16; ++v) {
      int row = crow0 + mi * 32 + (v & 3) + 8 * (v >> 2);
      C[(size_t)row * N_DIM + ccol0]      = acc[mi][0][v] + bv0;
      C[(size_t)row * N_DIM + ccol0 + 32] = acc[mi][1][v] + bv1;
    }
}

extern "C" void kernel_launch(void* const* d_in, const int* in_sizes, int n_in,
                              void* d_out, int out_size, void* d_ws, size_t ws_size,
                              hipStream_t stream) {
  const float* x  = (const float*)d_in[0];   // [M, K]
  const float* W  = (const float*)d_in[1];   // [N, K]
  const float* b  = (const float*)d_in[2];   // [N]
  const float* lA = (const float*)d_in[3];   // [R, K]
  const float* lB = (const float*)d_in[4];   // [N, R]
  float* out = (float*)d_out;                // [M, N]

  const int M = in_sizes[0] / K_DIM;  // 8192

  ushort* xb = (ushort*)d_ws;                 // 64 MB (swizzled layout)
  ushort* wb = xb + (size_t)M * K_DIM;        // 32 MB (swizzled layout)

  long n4 = (long)M * K_DIM / 4;
  prepass_kernel<<<N_DIM + 2048, 256, 0, stream>>>(x, xb, W, lA, lB, wb, n4);
  gemm_lora_kernel<<<(M / BM) * (N_DIM / BN), 512, 0, stream>>>(xb, wb, b, out);
}

// Round 8
// 298.407 us; speedup vs baseline: 1.1804x; 1.1804x over previous
//
#include <hip/hip_runtime.h>
#include <hip/hip_bf16.h>

#define K_DIM 4096
#define N_DIM 4096
#define R_DIM 16
#define SCALING_F 2.0f

#define BM 256
#define BN 256
#define BK 64   // bf16 elems per K-tile; 128 bytes per LDS row

#define FOLD_ROWS 8
#define FOLD_BLOCKS (N_DIM / FOLD_ROWS)   // 512

typedef __attribute__((ext_vector_type(8))) short bf16x8;
typedef __attribute__((ext_vector_type(4))) float f32x4;

__device__ __forceinline__ ushort f2bf(float f) {
  union { float f; unsigned u; } v; v.f = f;
  unsigned u = v.u;
  u += 0x7FFF + ((u >> 16) & 1);   // round-to-nearest-even
  return (ushort)(u >> 16);
}

// ---- fused pre-pass ----
// blocks [0,512): W-fold, 8 rows/block with A-chunk register cache (A re-read
// drops 4096x256KB=1GB -> 512x256KB=128MB of L2 traffic).
// blocks [512,2560): x fp32->bf16 convert, linear.
__global__ __launch_bounds__(256) void prepass_kernel(
    const float* __restrict__ x, ushort* __restrict__ xb,
    const float* __restrict__ W, const float* __restrict__ A,
    const float* __restrict__ Bl, ushort* __restrict__ wb, long n4) {
  if (blockIdx.x < FOLD_BLOCKS) {
    const int o0 = blockIdx.x * FOLD_ROWS;
#pragma unroll 1
    for (int j = 0; j < 4; ++j) {
      const int d0 = (threadIdx.x + j * 256) * 4;
      float4 a[R_DIM];
#pragma unroll
      for (int r = 0; r < R_DIM; ++r)
        a[r] = *(const float4*)(A + (size_t)r * K_DIM + d0);
#pragma unroll 1
      for (int rr = 0; rr < FOLD_ROWS; ++rr) {
        const int o = o0 + rr;
        float4 w = *(const float4*)(W + (size_t)o * K_DIM + d0);
        float s0 = w.x, s1 = w.y, s2 = w.z, s3 = w.w;
#pragma unroll
        for (int r = 0; r < R_DIM; ++r) {
          const float bv = Bl[o * R_DIM + r] * SCALING_F;  // uniform -> sgpr
          s0 += bv * a[r].x; s1 += bv * a[r].y;
          s2 += bv * a[r].z; s3 += bv * a[r].w;
        }
        ushort4 ob;
        ob.x = f2bf(s0); ob.y = f2bf(s1); ob.z = f2bf(s2); ob.w = f2bf(s3);
        *(ushort4*)(wb + (size_t)o * K_DIM + d0) = ob;
      }
    }
  } else {
    long i = (long)(blockIdx.x - FOLD_BLOCKS) * blockDim.x + threadIdx.x;
    long stride = 2048L * blockDim.x;
    for (; i < n4; i += stride) {
      long idx = i * 4;
      float4 v = *(const float4*)(x + idx);
      ushort4 o;
      o.x = f2bf(v.x); o.y = f2bf(v.y); o.z = f2bf(v.z); o.w = f2bf(v.w);
      *(ushort4*)(xb + idx) = o;
    }
  }
}

// ============================ 256x256 4-phase GEMM ============================
// r6 base (16x16x32 MFMA, 0-conflict 3-bit XOR swizzle, global_load_lds
// staging, same-reg post-MFMA frag prefetch) with phases merged 8->4:
// 32 MFMA per phase, half the barriers. Ledger (verified):
//   reads by phase-end prefetch: ph1: A-odd-buf0 | ph2: B-buf1 + A-even-buf1
//     | ph3: A-odd-buf1 | ph4: B-buf0 + A-even-buf0 (next tile-pair)
//   stages (issue at phase start): ph1: Ao(t1->buf1) | ph2: B0,B1,Ae(t2->buf0)
//     | ph3: Ao(t2->buf0) | ph4: B0,B1,Ae(t3->buf1)
//   counted waits at phase close: vmcnt(2),(6),(2),(6) — each drains loads
//   issued >=1 full phase earlier; close-barrier publishes before any read.
//   Last iter: ph2-close waits vmcnt(0) (must drain Ao(t63) for ph3's PF).

#define RS 8192L  // global row stride bytes (K_DIM * 2)

#define GLOAD(SRC, LOFF)                                                    \
  __builtin_amdgcn_global_load_lds(                                         \
      (const __attribute__((address_space(1))) void*)(SRC),                 \
      (__attribute__((address_space(3))) void*)(smem + (LOFF)), 16, 0, 0)

#define LDSA(BUF) ((BUF) * 32768)
#define LDSB(BUF) (65536 + (BUF) * 32768)

#define ST_A_EVEN(T, BUF) do {                                              \
    GLOAD(aS + (size_t)(T) * 128,            LDSA(BUF) + ldsDst);           \
    GLOAD(aS + (size_t)(T) * 128 + 128 * RS, LDSA(BUF) + 16384 + ldsDst); } while (0)
#define ST_A_ODD(T, BUF) do {                                               \
    GLOAD(aS + (size_t)(T) * 128 + 64 * RS,  LDSA(BUF) + 8192 + ldsDst);    \
    GLOAD(aS + (size_t)(T) * 128 + 192 * RS, LDSA(BUF) + 24576 + ldsDst); } while (0)
#define ST_B_H0(T, BUF) do {                                                \
    GLOAD(bS + (size_t)(T) * 128,            LDSB(BUF) + ldsDst);           \
    GLOAD(bS + (size_t)(T) * 128 + 64 * RS,  LDSB(BUF) + 8192 + ldsDst); } while (0)
#define ST_B_H1(T, BUF) do {                                                \
    GLOAD(bS + (size_t)(T) * 128 + 128 * RS, LDSB(BUF) + 16384 + ldsDst);   \
    GLOAD(bS + (size_t)(T) * 128 + 192 * RS, LDSB(BUF) + 24576 + ldsDst); } while (0)

#define LDA(M, CK, BUF) (*(const bf16x8*)(smem + LDSA(BUF) + aRd + (M) * 2048 + (CK)))
#define LDB(N, CK, BUF) (*(const bf16x8*)(smem + LDSB(BUF) + bRd + (N) * 2048 + (CK)))

// prefetch into the SAME afr/bfr registers (WAR keeps them post-MFMA)
#define PF_A8(MB, BUF) do {                                                 \
    afr[0][0] = LDA((MB) + 0, cK0, BUF); afr[0][1] = LDA((MB) + 0, cK1, BUF); \
    afr[1][0] = LDA((MB) + 1, cK0, BUF); afr[1][1] = LDA((MB) + 1, cK1, BUF); \
    afr[2][0] = LDA((MB) + 2, cK0, BUF); afr[2][1] = LDA((MB) + 2, cK1, BUF); \
    afr[3][0] = LDA((MB) + 3, cK0, BUF); afr[3][1] = LDA((MB) + 3, cK1, BUF); } while (0)

#define PF_B8(BUF) do {                                                     \
    bfr[0][0] = LDB(0, cK0, BUF); bfr[0][1] = LDB(0, cK1, BUF);             \
    bfr[1][0] = LDB(1, cK0, BUF); bfr[1][1] = LDB(1, cK1, BUF);             \
    bfr[2][0] = LDB(2, cK0, BUF); bfr[2][1] = LDB(2, cK1, BUF);             \
    bfr[3][0] = LDB(3, cK0, BUF); bfr[3][1] = LDB(3, cK1, BUF); } while (0)

#define MFMA32(MB) do {                                                     \
    _Pragma("unroll") for (int mm = 0; mm < 4; ++mm)                        \
      _Pragma("unroll") for (int nn = 0; nn < 4; ++nn) {                    \
        acc[(MB) + mm][nn] = __builtin_amdgcn_mfma_f32_16x16x32_bf16(       \
            afr[mm][0], bfr[nn][0], acc[(MB) + mm][nn], 0, 0, 0);           \
        acc[(MB) + mm][nn] = __builtin_amdgcn_mfma_f32_16x16x32_bf16(       \
            afr[mm][1], bfr[nn][1], acc[(MB) + mm][nn], 0, 0, 0); } } while (0)

#define PH_OPEN() do {                                                      \
    __builtin_amdgcn_s_barrier();                                           \
    asm volatile("s_waitcnt lgkmcnt(0)");                                   \
    __builtin_amdgcn_s_setprio(1); } while (0)

__global__ __launch_bounds__(512, 2) void gemm_lora_kernel(
    const ushort* __restrict__ Ab, const ushort* __restrict__ Bb,
    const float* __restrict__ bias, float* __restrict__ C) {
  __shared__ char smem[131072];

  const int tid = threadIdx.x;
  const int wave = tid >> 6, lane = tid & 63;
  const int wm = wave >> 2, wn = wave & 3;
  const int fr = lane & 15, fq = lane >> 4;

  // XCD-aware mapping: XCD x owns bm in [4x,4x+4); bn sweeps. grid=512 (%8==0).
  const int bid = blockIdx.x;
  const int bm = ((bid & 7) << 2) + ((bid >> 3) & 3);
  const int bn = bid >> 5;

  // staging source (inverse-swizzled global addresses, 16B chunks)
  const int trow = tid >> 3;
  const int tswz = ((tid & 7) << 4) ^ ((trow & 7) << 4);
  const char* aS = (const char*)Ab + (size_t)(bm * BM + trow) * RS + tswz;
  const char* bS = (const char*)Bb + (size_t)(bn * BN + trow) * RS + tswz;
  const int ldsDst = tid << 4;

  // swizzled ds_read byte columns (verified 0-conflict r2/r5/r6)
  const int sa  = (fr & 7) << 4;
  const int cK0 = (fq << 4) ^ sa;
  const int cK1 = (64 | (fq << 4)) ^ sa;
  const int aRd = ((wm << 7) + fr) << 7;   // (wm*128 + fr) * 128 B
  const int bRd = ((wn << 6) + fr) << 7;   // (wn*64  + fr) * 128 B

  f32x4 acc[8][4];
#pragma unroll
  for (int m = 0; m < 8; ++m)
#pragma unroll
    for (int n = 0; n < 4; ++n) acc[m][n] = (f32x4){0.f, 0.f, 0.f, 0.f};
  bf16x8 afr[4][2], bfr[4][2];

  // prologue: tile0 -> buf0 (full); tile1 -> buf1 (B0,B1,Ae). 14 loads.
  ST_B_H0(0, 0); ST_B_H1(0, 0); ST_A_EVEN(0, 0); ST_A_ODD(0, 0);
  ST_B_H0(1, 1); ST_B_H1(1, 1); ST_A_EVEN(1, 1);
  asm volatile("s_waitcnt vmcnt(6)" ::: "memory");  // tile0 fully landed
  __builtin_amdgcn_s_barrier();                      // ...and visible to all
  PF_B8(0);       // B-buf0 frags
  PF_A8(0, 0);    // A-even-buf0 (m0-3) frags

  const int NIT = K_DIM / (2 * BK);  // 32
#pragma unroll 1
  for (int i = 0; i < NIT; ++i) {
    const int t1 = 2 * i + 1, t2 = 2 * i + 2, t3 = 2 * i + 3;
    const bool last = (i == NIT - 1);

    // ---- phase 1: buf0, m0-3 ----
    ST_A_ODD(t1, 1);
    PH_OPEN();
    MFMA32(0);
    __builtin_amdgcn_s_setprio(0);
    PF_A8(4, 0);                            // prefetch ph2 frags (A-odd-buf0)
    asm volatile("s_waitcnt vmcnt(2)" ::: "memory");  // drain B0,B1,Ae(t1)
    __builtin_amdgcn_s_barrier();

    // ---- phase 2: buf0, m4-7 ----
    if (!last) { ST_B_H0(t2, 0); ST_B_H1(t2, 0); ST_A_EVEN(t2, 0); }
    PH_OPEN();
    MFMA32(4);
    __builtin_amdgcn_s_setprio(0);
    PF_B8(1);                               // prefetch ph3 frags (buf1)
    PF_A8(0, 1);
    if (last) asm volatile("s_waitcnt vmcnt(0)" ::: "memory");  // drain Ao(t63)
    else      asm volatile("s_waitcnt vmcnt(6)" ::: "memory");  // drain Ao(t1)
    __builtin_amdgcn_s_barrier();

    // ---- phase 3: buf1, m0-3 ----
    if (!last) ST_A_ODD(t2, 0);
    PH_OPEN();
    MFMA32(0);
    __builtin_amdgcn_s_setprio(0);
    PF_A8(4, 1);                            // prefetch ph4 frags (A-odd-buf1)
    if (!last) asm volatile("s_waitcnt vmcnt(2)" ::: "memory"); // drain t2 B,Ae
    __builtin_amdgcn_s_barrier();

    // ---- phase 4: buf1, m4-7 ----
    if (!last) { ST_B_H0(t3, 1); ST_B_H1(t3, 1); ST_A_EVEN(t3, 1); }
    PH_OPEN();
    MFMA32(4);
    __builtin_amdgcn_s_setprio(0);
    if (!last) {
      PF_B8(0);                             // prefetch next-iter ph1 frags
      PF_A8(0, 0);
      asm volatile("s_waitcnt vmcnt(6)" ::: "memory");  // drain Ao(t2)
      __builtin_amdgcn_s_barrier();
    }
  }

  // epilogue: C/D layout col=lane&15, row=(lane>>4)*4+reg  [m89/m91]
  const int ccol0 = bn * BN + wn * 64 + fr;
  float bv[4];
#pragma unroll
  for (int n = 0; n < 4; ++n) bv[n] = bias[ccol0 + n * 16];
  const int crow0 = bm * BM + wm * 128 + fq * 4;
#pragma unroll
  for (int m = 0; m < 8; ++m)
#pragma unroll
    for (int n = 0; n < 4; ++n)
#pragma unroll
      for (int v = 0; v < 4; ++v) {
        int row = crow0 + m * 16 + v;
        C[(size_t)row * N_DIM + ccol0 + n * 16] = acc[m][n][v] + bv[n];
      }
}

extern "C" void kernel_launch(void* const* d_in, const int* in_sizes, int n_in,
                              void* d_out, int out_size, void* d_ws, size_t ws_size,
                              hipStream_t stream) {
  const float* x  = (const float*)d_in[0];   // [M, K]
  const float* W  = (const float*)d_in[1];   // [N, K]
  const float* b  = (const float*)d_in[2];   // [N]
  const float* lA = (const float*)d_in[3];   // [R, K]
  const float* lB = (const float*)d_in[4];   // [N, R]
  float* out = (float*)d_out;                // [M, N]

  const int M = in_sizes[0] / K_DIM;  // 8192

  ushort* xb = (ushort*)d_ws;                 // 64 MB
  ushort* wb = xb + (size_t)M * K_DIM;        // 32 MB

  long n4 = (long)M * K_DIM / 4;
  prepass_kernel<<<FOLD_BLOCKS + 2048, 256, 0, stream>>>(x, xb, W, lA, lB, wb, n4);
  gemm_lora_kernel<<<(M / BM) * (N_DIM / BN), 512, 0, stream>>>(xb, wb, b, out);
}